// Round 2
// baseline (713.872 us; speedup 1.0000x reference)
//
#include <hip/hip_runtime.h>
#include <math.h>

#define EPSBN 1e-5f

// ---------------------------------------------------------------------------
// Kernel 1: time-average. Output element o = mean(x[25o .. 25o+24]).
// Block = 256 threads, handles 256 outputs = 6400 contiguous input floats.
// Memory-bound: 389 MB read once, perfectly coalesced via LDS staging.
// (At HBM roofline; untouched.)
// ---------------------------------------------------------------------------
__global__ __launch_bounds__(256)
void mean25_kernel(const float* __restrict__ x, float* __restrict__ h1)
{
    __shared__ __align__(16) float s[6400];
    const int t = threadIdx.x;
    const float4* xv = (const float4*)(x + (size_t)blockIdx.x * 6400);
    float4* sv = (float4*)s;
#pragma unroll
    for (int i = 0; i < 6; ++i) sv[i * 256 + t] = xv[i * 256 + t];
    if (t < 64) sv[1536 + t] = xv[1536 + t];   // 1600 float4 total
    __syncthreads();
    const float* p = s + t * 25;               // stride 25, coprime to 32 banks
    float acc = 0.f;
#pragma unroll
    for (int k = 0; k < 25; ++k) acc += p[k];
    h1[(size_t)blockIdx.x * 256 + t] = acc * (1.0f / 25.0f);
}

// ---------------------------------------------------------------------------
// Kernel 2 (GEMM1): C[m,n] = BN_e( relu( sum_k A[m,k]*W[n,k] + bias[n] ) )
// BN per-electrode (e = m % 19). 64x64 tile, BK=32, 256 thr, 4x4/thread.
// LDS row stride 68 floats: staging-write conflicts 4-way (was 8-way),
// fragment reads broadcast/2-way (free). Near the f32 VALU floor; untouched.
// ---------------------------------------------------------------------------
__global__ __launch_bounds__(256)
void sgemm_relu_bnch(const float* __restrict__ A, const float* __restrict__ W,
                     const float* __restrict__ bias,
                     const float* __restrict__ bg, const float* __restrict__ bb,
                     const float* __restrict__ brm, const float* __restrict__ brv,
                     float* __restrict__ C, int M, int N, int K)
{
    __shared__ __align__(16) float As[32][68];
    __shared__ __align__(16) float Ws[32][68];
    const int tid = threadIdx.x;
    const int bm = blockIdx.y * 64;
    const int bn = blockIdx.x * 64;
    const int tm0 = (tid >> 4) * 4;        // 0..60
    const int tn0 = (tid & 15) * 4;        // 0..60
    const int r0 = tid >> 3;               // 0..31
    const int c0 = (tid & 7) * 4;          // 0,4,..,28

    float acc[4][4] = {};
    const float* A0 = A + (size_t)(bm + r0) * K + c0;
    const float* A1 = A + (size_t)(bm + r0 + 32) * K + c0;
    const float* W0 = W + (size_t)(bn + r0) * K + c0;
    const float* W1 = W + (size_t)(bn + r0 + 32) * K + c0;

    float4 a0 = *(const float4*)A0;
    float4 a1 = *(const float4*)A1;
    float4 w0 = *(const float4*)W0;
    float4 w1 = *(const float4*)W1;

    for (int k0 = 0; k0 < K; k0 += 32) {
        __syncthreads();                   // previous iter's readers done
        As[c0 + 0][r0] = a0.x; As[c0 + 1][r0] = a0.y;
        As[c0 + 2][r0] = a0.z; As[c0 + 3][r0] = a0.w;
        As[c0 + 0][r0 + 32] = a1.x; As[c0 + 1][r0 + 32] = a1.y;
        As[c0 + 2][r0 + 32] = a1.z; As[c0 + 3][r0 + 32] = a1.w;
        Ws[c0 + 0][r0] = w0.x; Ws[c0 + 1][r0] = w0.y;
        Ws[c0 + 2][r0] = w0.z; Ws[c0 + 3][r0] = w0.w;
        Ws[c0 + 0][r0 + 32] = w1.x; Ws[c0 + 1][r0 + 32] = w1.y;
        Ws[c0 + 2][r0 + 32] = w1.z; Ws[c0 + 3][r0 + 32] = w1.w;
        __syncthreads();
        if (k0 + 32 < K) {                 // prefetch next tile (hidden by FMAs)
            a0 = *(const float4*)(A0 + k0 + 32);
            a1 = *(const float4*)(A1 + k0 + 32);
            w0 = *(const float4*)(W0 + k0 + 32);
            w1 = *(const float4*)(W1 + k0 + 32);
        }
#pragma unroll
        for (int kk = 0; kk < 32; ++kk) {
            float4 a = *(const float4*)&As[kk][tm0];
            float4 b = *(const float4*)&Ws[kk][tn0];
            acc[0][0] += a.x * b.x; acc[0][1] += a.x * b.y;
            acc[0][2] += a.x * b.z; acc[0][3] += a.x * b.w;
            acc[1][0] += a.y * b.x; acc[1][1] += a.y * b.y;
            acc[1][2] += a.y * b.z; acc[1][3] += a.y * b.w;
            acc[2][0] += a.z * b.x; acc[2][1] += a.z * b.y;
            acc[2][2] += a.z * b.z; acc[2][3] += a.z * b.w;
            acc[3][0] += a.w * b.x; acc[3][1] += a.w * b.y;
            acc[3][2] += a.w * b.z; acc[3][3] += a.w * b.w;
        }
    }

    const float b0 = bias[bn + tn0 + 0];
    const float b1 = bias[bn + tn0 + 1];
    const float b2 = bias[bn + tn0 + 2];
    const float b3 = bias[bn + tn0 + 3];
#pragma unroll
    for (int i = 0; i < 4; ++i) {
        const int row = bm + tm0 + i;
        const int e = row % 19;
        const float scale = bg[e] * (1.0f / sqrtf(brv[e] + EPSBN));
        const float shift = bb[e] - brm[e] * scale;
        float4 o;
        o.x = fmaxf(acc[i][0] + b0, 0.f) * scale + shift;
        o.y = fmaxf(acc[i][1] + b1, 0.f) * scale + shift;
        o.z = fmaxf(acc[i][2] + b2, 0.f) * scale + shift;
        o.w = fmaxf(acc[i][3] + b3, 0.f) * scale + shift;
        *(float4*)(C + (size_t)row * N + bn + tn0) = o;
    }
}

// ---------------------------------------------------------------------------
// Kernel 3 (NEW): whole tail fused per graph.
// One block (256 thr) per graph; 1 block/CU (grid 256 == CU count).
//   phase 1: C1(19x128) = BN4(relu(h2[19x256] @ w3^T + b3))     (LDS)
//   phase 2: sh4(19x64) = BN5(relu(C1 @ w4^T + b4))             (LDS)
//   then GC1+BN6+GC2+BN7+maxpool+lin5+heads (previous graph_head body).
// Eliminates: gemm23's per-32-row weight staging, the h4 global round-trip,
// and two kernel-launch gaps.  Per-graph BN electrode index == row index.
// Row 19 is a zero-padded junk row (19 -> 20 for clean 2/4-way thread maps).
// ---------------------------------------------------------------------------
__global__ __launch_bounds__(256)
void tail_fused(const float* __restrict__ h2,
                const int* __restrict__ ei,
                const float* __restrict__ w3, const float* __restrict__ b3,
                const float* __restrict__ g4, const float* __restrict__ bb4,
                const float* __restrict__ rm4, const float* __restrict__ rv4,
                const float* __restrict__ w4, const float* __restrict__ b4,
                const float* __restrict__ g5, const float* __restrict__ bb5,
                const float* __restrict__ rm5, const float* __restrict__ rv5,
                const float* __restrict__ ew1, const float* __restrict__ ew2,
                const float* __restrict__ wrel1, const float* __restrict__ brel1,
                const float* __restrict__ wroot1,
                const float* __restrict__ g6, const float* __restrict__ b6,
                const float* __restrict__ rm6, const float* __restrict__ rv6,
                const float* __restrict__ wrel2, const float* __restrict__ brel2,
                const float* __restrict__ wroot2,
                const float* __restrict__ g7, const float* __restrict__ b7,
                const float* __restrict__ rm7, const float* __restrict__ rv7,
                const float* __restrict__ lin5w, const float* __restrict__ lin5b,
                const float* __restrict__ hmw, const float* __restrict__ hmb,
                const float* __restrict__ hbw, const float* __restrict__ hbb,
                const float* __restrict__ hdw, const float* __restrict__ hdb,
                float* __restrict__ out, int nB, int nEdgeTot)
{
    __shared__ __align__(16) float sH2[20][260];   // 20.8 KB h2 rows (pad row)
    __shared__ __align__(16) float w3c[128][36];   // 18.4 KB w3 k-chunk, n-major
    __shared__ __align__(16) float C1[20][132];    // 10.6 KB lin3 out
    __shared__ __align__(16) float W4T[128][68];   // 34.8 KB lin4, k-major
    __shared__ __align__(16) float sh4[20][68];    //  5.4 KB lin4 out (features)
    __shared__ __align__(16) float sagg[19][68];   //  5.2 KB GC1 aggregate
    __shared__ __align__(16) float sh2g[19 * 32];
    __shared__ __align__(16) float sagg2[19 * 32];
    __shared__ __align__(16) float sh3[19 * 32];
    __shared__ __align__(16) float swrel1[2048];
    __shared__ __align__(16) float swroot1[2048];
    __shared__ __align__(16) float swrel2[1024];
    __shared__ __align__(16) float swroot2[1024];
    __shared__ __align__(16) float slin5[1024];
    __shared__ float s4s[19], s4h[19], s5s[19], s5h[19];
    __shared__ float sz[32], szz[32];
    __shared__ int ssrc[60], sdst[60];
    __shared__ float sew1[60], sew2[60];

    const int t = threadIdx.x;
    const int g = blockIdx.x;

    // ---- stage everything independent of compute up front ----
    {
        const float4* src = (const float4*)(h2 + (size_t)g * 19 * 256);
        for (int f = t; f < 1216; f += 256) {          // 19 rows x 64 float4
            const int row = f >> 6, c4 = f & 63;
            *((float4*)&sH2[row][c4 * 4]) = src[f];
        }
        if (t < 65) *((float4*)&sH2[19][t * 4]) = make_float4(0.f, 0.f, 0.f, 0.f);
    }
    for (int i = t; i < 2048; i += 256) { swrel1[i] = wrel1[i]; swroot1[i] = wroot1[i]; }
    for (int i = t; i < 1024; i += 256) { swrel2[i] = wrel2[i]; swroot2[i] = wroot2[i]; slin5[i] = lin5w[i]; }
    for (int i = t; i < 19 * 68; i += 256) ((float*)sagg)[i] = 0.f;
    for (int i = t; i < 19 * 32; i += 256) sagg2[i] = 0.f;
    if (t < 60) {
        ssrc[t] = ei[g * 60 + t] - g * 19;
        sdst[t] = ei[nEdgeTot + g * 60 + t] - g * 19;
        sew1[t] = ew1[t];
        sew2[t] = ew2[t];
    } else if (t >= 64 && t < 83) {                    // BN4 affine fold
        const int e = t - 64;
        const float sc = g4[e] * (1.0f / sqrtf(rv4[e] + EPSBN));
        s4s[e] = sc; s4h[e] = bb4[e] - rm4[e] * sc;
    } else if (t >= 96 && t < 115) {                   // BN5 affine fold
        const int e = t - 96;
        const float sc = g5[e] * (1.0f / sqrtf(rv5[e] + EPSBN));
        s5s[e] = sc; s5h[e] = bb5[e] - rm5[e] * sc;
    }

    // ---- phase 1: lin3 (19x256 @ 256x128^T), n-per-thread-pair ----
    const int n1 = t >> 1;             // 0..127
    const int mh = (t & 1) * 10;       // rows mh..mh+9 (row 19 = zero pad)
    const int wn = t >> 3;             // loader row base 0..31
    const int wk = (t & 7) * 4;        // loader k-offset
    float acc1[10] = {};
    float4 wpre[4];
#pragma unroll
    for (int i = 0; i < 4; ++i)
        wpre[i] = *(const float4*)(w3 + (size_t)(wn + 32 * i) * 256 + wk);

    for (int kc = 0; kc < 8; ++kc) {
        const int k0 = kc * 32;
        __syncthreads();               // staging / previous-chunk readers done
#pragma unroll
        for (int i = 0; i < 4; ++i)
            *((float4*)&w3c[wn + 32 * i][wk]) = wpre[i];
        __syncthreads();
        if (kc < 7) {
#pragma unroll
            for (int i = 0; i < 4; ++i)
                wpre[i] = *(const float4*)(w3 + (size_t)(wn + 32 * i) * 256 + wk + k0 + 32);
        }
#pragma unroll
        for (int k4 = 0; k4 < 8; ++k4) {
            const float4 w = *(const float4*)&w3c[n1][k4 * 4];
#pragma unroll
            for (int r = 0; r < 10; ++r) {
                const float4 a = *(const float4*)&sH2[mh + r][k0 + k4 * 4];
                acc1[r] += a.x * w.x + a.y * w.y + a.z * w.z + a.w * w.w;
            }
        }
    }
    // epilogue 1 -> C1 (LDS); BN4 per electrode (= row)
    {
        const float bn = b3[n1];
#pragma unroll
        for (int r = 0; r < 10; ++r) {
            const int row = mh + r;
            const int e = (row < 19) ? row : 0;
            C1[row][n1] = fmaxf(acc1[r] + bn, 0.f) * s4s[e] + s4h[e];
        }
    }

    // stage lin4 transposed (k-major rows, n-contiguous): conflict-free writes
    {
        const int ln = t & 63, wq = t >> 6;
#pragma unroll
        for (int ii = 0; ii < 8; ++ii) {
            const int c4 = wq + ii * 4;
            const float4 v = *(const float4*)(w4 + (size_t)ln * 128 + c4 * 4);
            W4T[c4 * 4 + 0][ln] = v.x;
            W4T[c4 * 4 + 1][ln] = v.y;
            W4T[c4 * 4 + 2][ln] = v.z;
            W4T[c4 * 4 + 3][ln] = v.w;
        }
    }
    __syncthreads();                   // C1 + W4T ready

    // ---- phase 2: lin4 (19x128 @ 128x64^T) ----
    const int n2 = t & 63;             // 0..63
    const int mq = (t >> 6) * 5;       // rows mq..mq+4 (row 19 = junk)
    float acc2[5] = {};
    for (int k4 = 0; k4 < 32; ++k4) {
        const float ww0 = W4T[k4 * 4 + 0][n2];
        const float ww1 = W4T[k4 * 4 + 1][n2];
        const float ww2 = W4T[k4 * 4 + 2][n2];
        const float ww3 = W4T[k4 * 4 + 3][n2];
#pragma unroll
        for (int r = 0; r < 5; ++r) {
            const float4 a = *(const float4*)&C1[mq + r][k4 * 4];
            acc2[r] += a.x * ww0 + a.y * ww1 + a.z * ww2 + a.w * ww3;
        }
    }
    // epilogue 2 -> sh4 (LDS); BN5 per electrode (= row)
    {
        const float bn = b4[n2];
#pragma unroll
        for (int r = 0; r < 5; ++r) {
            const int row = mq + r;
            const int e = (row < 19) ? row : 0;
            sh4[row][n2] = fmaxf(acc2[r] + bn, 0.f) * s5s[e] + s5h[e];
        }
    }
    __syncthreads();

    // ---- graph section (identical structure to previous graph_head) ----
    if (t < 64) {
        for (int e = 0; e < 60; ++e)
            sagg[sdst[e]][t] += sew1[e] * sh4[ssrc[e]][t];
    }
    __syncthreads();

    for (int idx = t; idx < 19 * 32; idx += 256) {
        const int n = idx >> 5, j = idx & 31;
        const float4* ag = (const float4*)&sagg[n][0];
        const float4* hg = (const float4*)&sh4[n][0];
        const float4* wr = (const float4*)&swrel1[j * 64];
        const float4* wo = (const float4*)&swroot1[j * 64];
        float acc = brel1[j];
#pragma unroll
        for (int k = 0; k < 16; ++k) {
            float4 a = ag[k], w = wr[k], x = hg[k], u = wo[k];
            acc += a.x * w.x + a.y * w.y + a.z * w.z + a.w * w.w;
            acc += x.x * u.x + x.y * u.y + x.z * u.z + x.w * u.w;
        }
        float v = fmaxf(acc, 0.f);
        const float scale = g6[j] * (1.0f / sqrtf(rv6[j] + EPSBN));
        sh2g[idx] = (v - rm6[j]) * scale + b6[j];
    }
    __syncthreads();

    if (t < 32) {
        for (int e = 0; e < 60; ++e)
            sagg2[sdst[e] * 32 + t] += sew2[e] * sh2g[ssrc[e] * 32 + t];
    }
    __syncthreads();

    for (int idx = t; idx < 19 * 32; idx += 256) {
        const int n = idx >> 5, j = idx & 31;
        const float4* ag = (const float4*)&sagg2[n * 32];
        const float4* hg = (const float4*)&sh2g[n * 32];
        const float4* wr = (const float4*)&swrel2[j * 32];
        const float4* wo = (const float4*)&swroot2[j * 32];
        float acc = brel2[j];
#pragma unroll
        for (int k = 0; k < 8; ++k) {
            float4 a = ag[k], w = wr[k], x = hg[k], u = wo[k];
            acc += a.x * w.x + a.y * w.y + a.z * w.z + a.w * w.w;
            acc += x.x * u.x + x.y * u.y + x.z * u.z + x.w * u.w;
        }
        float v = fmaxf(acc, 0.f);
        const float scale = g7[j] * (1.0f / sqrtf(rv7[j] + EPSBN));
        sh3[idx] = (v - rm7[j]) * scale + b7[j];
    }
    __syncthreads();

    if (t < 32) {
        float m = sh3[t];
        for (int n = 1; n < 19; ++n) m = fmaxf(m, sh3[n * 32 + t]);
        sz[t] = m;
    }
    __syncthreads();

    if (t < 32) {
        float acc = lin5b[t];
        const float4* zp = (const float4*)sz;
        const float4* wp = (const float4*)&slin5[t * 32];
#pragma unroll
        for (int k = 0; k < 8; ++k) {
            float4 z = zp[k], w = wp[k];
            acc += z.x * w.x + z.y * w.y + z.z * w.z + z.w * w.w;
        }
        szz[t] = fmaxf(acc, 0.f);
    }
    __syncthreads();

    if (t < 3) {
        float acc = hmb[t];
        for (int k = 0; k < 32; ++k) acc += szz[k] * hmw[t * 32 + k];
        out[g * 3 + t] = acc;
    } else if (t < 5) {
        const int j = t - 3;
        float acc = hbb[j];
        for (int k = 0; k < 32; ++k) acc += szz[k] * hbw[j * 32 + k];
        out[nB * 3 + g * 2 + j] = acc;
    } else if (t < 7) {
        const int j = t - 5;
        float acc = hdb[j];
        for (int k = 0; k < 32; ++k) acc += szz[k] * hdw[j * 32 + k];
        out[nB * 5 + g * 2 + j] = acc;
    }
}

// ---------------------------------------------------------------------------
extern "C" void kernel_launch(void* const* d_in, const int* in_sizes, int n_in,
                              void* d_out, int out_size, void* d_ws, size_t ws_size,
                              hipStream_t stream)
{
    const float* x       = (const float*)d_in[0];
    const int*   ei      = (const int*)d_in[1];
    const float* lin2_w  = (const float*)d_in[3];
    const float* lin2_b  = (const float*)d_in[4];
    const float* bn3_g   = (const float*)d_in[5];
    const float* bn3_b   = (const float*)d_in[6];
    const float* bn3_rm  = (const float*)d_in[7];
    const float* bn3_rv  = (const float*)d_in[8];
    const float* lin3_w  = (const float*)d_in[9];
    const float* lin3_b  = (const float*)d_in[10];
    const float* bn4_g   = (const float*)d_in[11];
    const float* bn4_b   = (const float*)d_in[12];
    const float* bn4_rm  = (const float*)d_in[13];
    const float* bn4_rv  = (const float*)d_in[14];
    const float* lin4_w  = (const float*)d_in[15];
    const float* lin4_b  = (const float*)d_in[16];
    const float* bn5_g   = (const float*)d_in[17];
    const float* bn5_b   = (const float*)d_in[18];
    const float* bn5_rm  = (const float*)d_in[19];
    const float* bn5_rv  = (const float*)d_in[20];
    const float* ew1     = (const float*)d_in[21];
    const float* gc1_wrel  = (const float*)d_in[22];
    const float* gc1_brel  = (const float*)d_in[23];
    const float* gc1_wroot = (const float*)d_in[24];
    const float* bn6_g   = (const float*)d_in[25];
    const float* bn6_b   = (const float*)d_in[26];
    const float* bn6_rm  = (const float*)d_in[27];
    const float* bn6_rv  = (const float*)d_in[28];
    const float* ew2     = (const float*)d_in[29];
    const float* gc2_wrel  = (const float*)d_in[30];
    const float* gc2_brel  = (const float*)d_in[31];
    const float* gc2_wroot = (const float*)d_in[32];
    const float* bn7_g   = (const float*)d_in[33];
    const float* bn7_b   = (const float*)d_in[34];
    const float* bn7_rm  = (const float*)d_in[35];
    const float* bn7_rv  = (const float*)d_in[36];
    const float* lin5_w  = (const float*)d_in[37];
    const float* lin5_b  = (const float*)d_in[38];
    const float* hm_w    = (const float*)d_in[39];
    const float* hm_b    = (const float*)d_in[40];
    const float* hb_w    = (const float*)d_in[41];
    const float* hb_b    = (const float*)d_in[42];
    const float* hd_w    = (const float*)d_in[43];
    const float* hd_b    = (const float*)d_in[44];

    const int n_nodes = in_sizes[0] / 20000;   // 4864
    const int B = n_nodes / 19;                // 256

    float* h1 = (float*)d_ws;                         // (n_nodes, 800)
    float* h2 = h1 + (size_t)n_nodes * 800;           // (n_nodes, 256)

    // 1) time-average
    mean25_kernel<<<(n_nodes * 800) / 256, 256, 0, stream>>>(x, h1);

    // 2) lin2 + relu + bn3
    dim3 g1(256 / 64, n_nodes / 64);
    sgemm_relu_bnch<<<g1, 256, 0, stream>>>(h1, lin2_w, lin2_b,
                                            bn3_g, bn3_b, bn3_rm, bn3_rv,
                                            h2, n_nodes, 256, 800);

    // 3) whole tail, fused per graph
    tail_fused<<<B, 256, 0, stream>>>(h2, ei,
                                      lin3_w, lin3_b,
                                      bn4_g, bn4_b, bn4_rm, bn4_rv,
                                      lin4_w, lin4_b,
                                      bn5_g, bn5_b, bn5_rm, bn5_rv,
                                      ew1, ew2,
                                      gc1_wrel, gc1_brel, gc1_wroot,
                                      bn6_g, bn6_b, bn6_rm, bn6_rv,
                                      gc2_wrel, gc2_brel, gc2_wroot,
                                      bn7_g, bn7_b, bn7_rm, bn7_rv,
                                      lin5_w, lin5_b,
                                      hm_w, hm_b, hb_w, hb_b, hd_w, hd_b,
                                      (float*)d_out, B, B * 60);
}